// Round 1
// baseline (1502.164 us; speedup 1.0000x reference)
//
#include <hip/hip_runtime.h>
#include <hip/hip_cooperative_groups.h>

namespace cg = cooperative_groups;

#define NN 2048
#define MM 2048
#define KC 8
#define DD 64

#define LN2F    0.6931471805599453f
#define INVLN2F 1.4426950408889634f

struct Params {
  const float* x; const float* centers; const float* ftarg;
  const float* y; const int* predy;
  float* out;
  int* pred_x; int* cnt_x; int* cnt_y; int* off_x; int* off_y;
  int* fill_x; int* fill_y; int* pc_x; int* pc_y;
  int* boxy; int* boxx; int* boyy;
  float* Xp; float* Yp; float* xn; float* yn;
  float* Cxy; float* Cyx; float* Cxx; float* Cyy;
  float* Fab; float* Gab; float* Faa; float* Gbb;   // each 2*len (ping-pong)
  float* la; float* lb; int* valid;
  float* acc;
};

__device__ __forceinline__ float wredmax(float v){
  #pragma unroll
  for(int m=32;m>=1;m>>=1) v = fmaxf(v, __shfl_xor(v,m,64));
  return v;
}
__device__ __forceinline__ float wredsum(float v){
  #pragma unroll
  for(int m=32;m>=1;m>>=1) v += __shfl_xor(v,m,64);
  return v;
}

__global__ void __launch_bounds__(256,1) sinkhorn_all(Params p)
{
  cg::grid_group grid = cg::this_grid();
  const int tid  = threadIdx.x;
  const int gtid = blockIdx.x*blockDim.x + tid;
  const int nth  = gridDim.x*blockDim.x;
  const int lane = tid & 63;
  const int wid  = gtid >> 6;
  const int nwaves = nth >> 6;

  // eps schedule length (mirror python: double math, cast to f32 per step)
  const double EMIN = 0.05*0.05;       // BLUR**2 in double
  const double S2   = 0.8*0.8;         // SCALING**2 in double
  int neps = 0;
  { double e = 16.0; while(e > EMIN){ neps++; e *= S2; } neps++; }   // = 21

  // ---------- phase 0: zero init ----------
  for(int i=gtid;i<NN;i+=nth){ p.Fab[i]=0.f; p.Faa[i]=0.f; }
  for(int j=gtid;j<MM;j+=nth){ p.Gab[j]=0.f; p.Gbb[j]=0.f; }
  if(gtid<KC){ p.cnt_x[gtid]=0; p.cnt_y[gtid]=0; p.fill_x[gtid]=0; p.fill_y[gtid]=0; }
  if(gtid==0){ *p.acc = 0.f; }
  grid.sync();

  // ---------- phase 1: kmeans predict + counts ----------
  for(int i=gtid;i<NN;i+=nth){
    const float* xi = p.x + i*DD;
    float best = 3.4e38f; int bk = 0;
    for(int k=0;k<KC;k++){
      const float* ck = p.centers + k*DD;
      float s = 0.f;
      for(int d=0;d<DD;d++){ float df = xi[d]-ck[d]; s += df*df; }
      if(s < best){ best = s; bk = k; }   // strict <  -> first-min, matches argmin
    }
    p.pred_x[i] = bk;
    atomicAdd(&p.cnt_x[bk], 1);
  }
  for(int j=gtid;j<MM;j+=nth){
    atomicAdd(&p.cnt_y[p.predy[j]], 1);
  }
  grid.sync();

  // ---------- phase 2: prefix sums, log-weights, filling loss ----------
  if(gtid==0){
    int ox=0, oy=0, bxy=0, bxx=0, byy=0;
    float lf = 0.f;
    for(int k=0;k<KC;k++){
      int nk=p.cnt_x[k], mk=p.cnt_y[k];
      p.off_x[k]=ox; p.off_y[k]=oy;
      p.boxy[k]=bxy; p.boxx[k]=bxx; p.boyy[k]=byy;
      ox+=nk; oy+=mk; bxy+=nk*mk; bxx+=nk*nk; byy+=mk*mk;
      p.la[k] = -logf(fmaxf((float)nk,1.f));
      p.lb[k] = -logf(fmaxf((float)mk,1.f));
      p.valid[k] = (nk>0 && mk>0) ? 1 : 0;
      float df = (float)nk/(float)NN - p.ftarg[k];
      lf += df*df;
    }
    p.off_x[KC]=ox; p.off_y[KC]=oy;
    *p.acc += lf/(float)KC;
  }
  grid.sync();

  // ---------- phase 3: pack points by cluster ----------
  for(int i=gtid;i<NN;i+=nth){
    int k = p.pred_x[i];
    int pos = p.off_x[k] + atomicAdd(&p.fill_x[k],1);
    p.pc_x[pos] = k;
    const float* xi = p.x + i*DD; float* dst = p.Xp + pos*DD;
    float s=0.f;
    for(int d=0;d<DD;d++){ float v=xi[d]; dst[d]=v; s+=v*v; }
    p.xn[pos]=s;
  }
  for(int j=gtid;j<MM;j+=nth){
    int k = p.predy[j];
    int pos = p.off_y[k] + atomicAdd(&p.fill_y[k],1);
    p.pc_y[pos] = k;
    const float* yj = p.y + j*DD; float* dst = p.Yp + pos*DD;
    float s=0.f;
    for(int d=0;d<DD;d++){ float v=yj[d]; dst[d]=v; s+=v*v; }
    p.yn[pos]=s;
  }
  grid.sync();

  // ---------- phase 4: build packed per-cluster cost blocks ----------
  for(int k=0;k<KC;k++){
    const int nk=p.cnt_x[k], mk=p.cnt_y[k];
    const float4* Xb=(const float4*)(p.Xp + p.off_x[k]*DD);
    const float4* Yb=(const float4*)(p.Yp + p.off_y[k]*DD);
    const float* xnb=p.xn+p.off_x[k];
    const float* ynb=p.yn+p.off_y[k];
    int tot = nk*mk;
    for(int t=gtid;t<tot;t+=nth){
      int r=t/mk, c=t-r*mk;
      const float4* a=Xb+r*(DD/4); const float4* b=Yb+c*(DD/4);
      float dot=0.f;
      #pragma unroll
      for(int q=0;q<DD/4;q++){ float4 av=a[q], bv=b[q];
        dot += av.x*bv.x + av.y*bv.y + av.z*bv.z + av.w*bv.w; }
      float cst = 0.5f*fmaxf(xnb[r]+ynb[c]-2.f*dot, 0.f);
      p.Cxy[p.boxy[k]+t] = cst;
      p.Cyx[p.boxy[k]+c*nk+r] = cst;
    }
    tot = nk*nk;
    for(int t=gtid;t<tot;t+=nth){
      int r=t/nk, c=t-r*nk;
      const float4* a=Xb+r*(DD/4); const float4* b=Xb+c*(DD/4);
      float dot=0.f;
      #pragma unroll
      for(int q=0;q<DD/4;q++){ float4 av=a[q], bv=b[q];
        dot += av.x*bv.x + av.y*bv.y + av.z*bv.z + av.w*bv.w; }
      p.Cxx[p.boxx[k]+t] = 0.5f*fmaxf(xnb[r]+xnb[c]-2.f*dot, 0.f);
    }
    tot = mk*mk;
    for(int t=gtid;t<tot;t+=nth){
      int r=t/mk, c=t-r*mk;
      const float4* a=Yb+r*(DD/4); const float4* b=Yb+c*(DD/4);
      float dot=0.f;
      #pragma unroll
      for(int q=0;q<DD/4;q++){ float4 av=a[q], bv=b[q];
        dot += av.x*bv.x + av.y*bv.y + av.z*bv.z + av.w*bv.w; }
      p.Cyy[p.boyy[k]+t] = 0.5f*fmaxf(ynb[r]+ynb[c]-2.f*dot, 0.f);
    }
  }
  grid.sync();

  // ---------- phase 5: 21 eps-scaling Jacobi iterations ----------
  const int TOTROWS = 2*(NN+MM);
  double e_run = 16.0;
  int cur = 0;
  for(int it=0; it<neps; ++it){
    float eps = (it==neps-1) ? (float)EMIN : (float)e_run;
    e_run *= S2;
    float inv_eps = 1.0f/eps;
    const float* Fab_o=p.Fab+cur*NN; float* Fab_n=p.Fab+(1-cur)*NN;
    const float* Gab_o=p.Gab+cur*MM; float* Gab_n=p.Gab+(1-cur)*MM;
    const float* Faa_o=p.Faa+cur*NN; float* Faa_n=p.Faa+(1-cur)*NN;
    const float* Gbb_o=p.Gbb+cur*MM; float* Gbb_n=p.Gbb+(1-cur)*MM;

    for(int row=wid; row<TOTROWS; row+=nwaves){
      int grp, pidx;
      if(row < NN){ grp=0; pidx=row; }
      else if(row < NN+MM){ grp=1; pidx=row-NN; }
      else if(row < 2*NN+MM){ grp=2; pidx=row-NN-MM; }
      else { grp=3; pidx=row-2*NN-MM; }

      int k, r, len; const float* Cb; const float* hv; float hc;
      if(grp==0){ k=p.pc_x[pidx]; r=pidx-p.off_x[k]; len=p.cnt_y[k];
        Cb=p.Cxy+p.boxy[k]+r*len; hv=Gab_o+p.off_y[k]; hc=p.lb[k]; }
      else if(grp==1){ k=p.pc_y[pidx]; r=pidx-p.off_y[k]; len=p.cnt_x[k];
        Cb=p.Cyx+p.boxy[k]+r*len; hv=Fab_o+p.off_x[k]; hc=p.la[k]; }
      else if(grp==2){ k=p.pc_x[pidx]; r=pidx-p.off_x[k]; len=p.cnt_x[k];
        Cb=p.Cxx+p.boxx[k]+r*len; hv=Faa_o+p.off_x[k]; hc=p.la[k]; }
      else { k=p.pc_y[pidx]; r=pidx-p.off_y[k]; len=p.cnt_y[k];
        Cb=p.Cyy+p.boyy[k]+r*len; hv=Gbb_o+p.off_y[k]; hc=p.lb[k]; }

      float wmax = -3.4e38f;
      for(int c=lane;c<len;c+=64){
        float wv = (hc + (hv[c]-Cb[c])*inv_eps)*INVLN2F;
        wmax = fmaxf(wmax, wv);
      }
      wmax = wredmax(wmax);
      float ssum = 0.f;
      for(int c=lane;c<len;c+=64){
        float wv = (hc + (hv[c]-Cb[c])*inv_eps)*INVLN2F;
        ssum += exp2f(wv - wmax);
      }
      ssum = wredsum(ssum);
      float L = (len>0) ? (-eps*LN2F*(wmax + log2f(ssum))) : 0.f;

      if(lane==0){
        if(grp==0)      Fab_n[pidx] = 0.5f*(Fab_o[pidx]+L);
        else if(grp==1) Gab_n[pidx] = 0.5f*(Gab_o[pidx]+L);
        else if(grp==2) Faa_n[pidx] = 0.5f*(Faa_o[pidx]+L);
        else            Gbb_n[pidx] = 0.5f*(Gbb_o[pidx]+L);
      }
    }
    cur ^= 1;
    grid.sync();
  }

  // ---------- phase 6: final extrapolation at eps_min + reduction ----------
  {
    float eps = (float)EMIN;
    float inv_eps = 1.0f/eps;
    const float* Fab_o=p.Fab+cur*NN;
    const float* Gab_o=p.Gab+cur*MM;
    const float* Faa_o=p.Faa+cur*NN;
    const float* Gbb_o=p.Gbb+cur*MM;

    for(int row=wid; row<TOTROWS; row+=nwaves){
      int grp, pidx;
      if(row < NN){ grp=0; pidx=row; }
      else if(row < NN+MM){ grp=1; pidx=row-NN; }
      else if(row < 2*NN+MM){ grp=2; pidx=row-NN-MM; }
      else { grp=3; pidx=row-2*NN-MM; }

      int k, r, len; const float* Cb; const float* hv; float hc;
      if(grp==0){ k=p.pc_x[pidx]; r=pidx-p.off_x[k]; len=p.cnt_y[k];
        Cb=p.Cxy+p.boxy[k]+r*len; hv=Gab_o+p.off_y[k]; hc=p.lb[k]; }
      else if(grp==1){ k=p.pc_y[pidx]; r=pidx-p.off_y[k]; len=p.cnt_x[k];
        Cb=p.Cyx+p.boxy[k]+r*len; hv=Fab_o+p.off_x[k]; hc=p.la[k]; }
      else if(grp==2){ k=p.pc_x[pidx]; r=pidx-p.off_x[k]; len=p.cnt_x[k];
        Cb=p.Cxx+p.boxx[k]+r*len; hv=Faa_o+p.off_x[k]; hc=p.la[k]; }
      else { k=p.pc_y[pidx]; r=pidx-p.off_y[k]; len=p.cnt_y[k];
        Cb=p.Cyy+p.boyy[k]+r*len; hv=Gbb_o+p.off_y[k]; hc=p.lb[k]; }

      float wmax = -3.4e38f;
      for(int c=lane;c<len;c+=64){
        float wv = (hc + (hv[c]-Cb[c])*inv_eps)*INVLN2F;
        wmax = fmaxf(wmax, wv);
      }
      wmax = wredmax(wmax);
      float ssum = 0.f;
      for(int c=lane;c<len;c+=64){
        float wv = (hc + (hv[c]-Cb[c])*inv_eps)*INVLN2F;
        ssum += exp2f(wv - wmax);
      }
      ssum = wredsum(ssum);
      float L = (len>0) ? (-eps*LN2F*(wmax + log2f(ssum))) : 0.f;

      if(lane==0 && p.valid[k]){
        float contrib;
        if(grp==0)      contrib =  L/(float)p.cnt_x[k];
        else if(grp==1) contrib =  L/(float)p.cnt_y[k];
        else if(grp==2) contrib = -L/(float)p.cnt_x[k];
        else            contrib = -L/(float)p.cnt_y[k];
        atomicAdd(p.acc, contrib);
      }
    }
  }
  grid.sync();
  if(gtid==0) p.out[0] = *p.acc;
}

extern "C" void kernel_launch(void* const* d_in, const int* in_sizes, int n_in,
                              void* d_out, int out_size, void* d_ws, size_t ws_size,
                              hipStream_t stream)
{
  Params p;
  p.x       = (const float*)d_in[0];
  p.centers = (const float*)d_in[1];
  p.ftarg   = (const float*)d_in[2];
  p.y       = (const float*)d_in[3];
  p.predy   = (const int*)d_in[4];
  p.out     = (float*)d_out;

  char* w = (char*)d_ws; size_t o = 0;
  auto A = [&](size_t bytes)->char*{ char* r = w + o; o = (o + bytes + 255) & ~(size_t)255; return r; };
  p.pred_x=(int*)A(NN*4);
  p.cnt_x=(int*)A(KC*4);  p.cnt_y=(int*)A(KC*4);
  p.off_x=(int*)A((KC+1)*4); p.off_y=(int*)A((KC+1)*4);
  p.fill_x=(int*)A(KC*4); p.fill_y=(int*)A(KC*4);
  p.pc_x=(int*)A(NN*4);   p.pc_y=(int*)A(MM*4);
  p.boxy=(int*)A(KC*4);   p.boxx=(int*)A(KC*4); p.boyy=(int*)A(KC*4);
  p.Xp=(float*)A((size_t)NN*DD*4); p.Yp=(float*)A((size_t)MM*DD*4);
  p.xn=(float*)A(NN*4);   p.yn=(float*)A(MM*4);
  p.Fab=(float*)A(2*NN*4); p.Gab=(float*)A(2*MM*4);
  p.Faa=(float*)A(2*NN*4); p.Gbb=(float*)A(2*MM*4);
  p.la=(float*)A(KC*4);   p.lb=(float*)A(KC*4); p.valid=(int*)A(KC*4);
  p.acc=(float*)A(4);
  p.Cxy=(float*)A((size_t)NN*MM*4);
  p.Cyx=(float*)A((size_t)NN*MM*4);
  p.Cxx=(float*)A((size_t)NN*NN*4);
  p.Cyy=(float*)A((size_t)MM*MM*4);

  void* args[] = { &p };
  hipLaunchCooperativeKernel((void*)sinkhorn_all, dim3(256), dim3(256), args, 0, stream);
}